// Round 2
// baseline (9842.233 us; speedup 1.0000x reference)
//
#include <hip/hip_runtime.h>
#include <stdint.h>

#define Bdim 4
#define Tdim 2048
#define Vdim 32000
#define Hdim 512
#define MROWS (Bdim * Tdim)   // 8192

typedef unsigned short u16;
typedef __bf16 bf16x8 __attribute__((ext_vector_type(8)));
typedef float f32x4 __attribute__((ext_vector_type(4)));

__device__ __forceinline__ u16 f2bf(float f) {
  union { float f; uint32_t u; } a; a.f = f;
  uint32_t r = a.u + 0x7FFFu + ((a.u >> 16) & 1u);
  return (u16)(r >> 16);
}

// ---------------- embedding gather -> bf16 ----------------
__global__ void k_gather(const int* __restrict__ x, const float* __restrict__ embed,
                         u16* __restrict__ E) {
  int idx = blockIdx.x * 256 + threadIdx.x;   // one float4 per thread
  int row = idx >> 7;                          // 128 float4 per row
  int c4  = (idx & 127) << 2;
  int tok = x[row];
  const float4 v = *(const float4*)(embed + (size_t)tok * Hdim + c4);
  *(ushort4*)(E + (size_t)row * Hdim + c4) =
      make_ushort4(f2bf(v.x), f2bf(v.y), f2bf(v.z), f2bf(v.w));
}

// ---------------- fp32 -> bf16 convert ----------------
__global__ void k_f2b(const float* __restrict__ in, u16* __restrict__ out, int n4) {
  int idx = blockIdx.x * 256 + threadIdx.x;
  if (idx >= n4) return;
  const float4 v = *(const float4*)(in + (size_t)idx * 4);
  *(ushort4*)(out + (size_t)idx * 4) =
      make_ushort4(f2bf(v.x), f2bf(v.y), f2bf(v.z), f2bf(v.w));
}

// ---------------- bf16 MFMA GEMM: C = A @ Bw^T + bias1 (+bias2) ----------------
__device__ __forceinline__ void g2l16(const void* g, void* l) {
  __builtin_amdgcn_global_load_lds(
      (const __attribute__((address_space(1))) uint32_t*)g,
      (__attribute__((address_space(3))) uint32_t*)l, 16, 0, 0);
}

__global__ __launch_bounds__(256, 2) void k_gemm(
    const u16* __restrict__ A, const u16* __restrict__ Bw, float* __restrict__ C,
    const float* __restrict__ bias1, const float* __restrict__ bias2,
    int M, int N, int K, int ntN)
{
  __shared__ u16 Al[128 * 64];
  __shared__ u16 Bl[128 * 64];
  const int bid = blockIdx.x;
  const int mt = bid / ntN, nt = bid % ntN;
  const int m0 = mt << 7, n0 = nt << 7;
  const int tid = threadIdx.x;
  const int l = tid & 63, w = tid >> 6;
  const int wy = w >> 1, wx = w & 1;
  const int frow = l & 15, fk = (l >> 4) << 3;

  f32x4 acc[4][4];
  #pragma unroll
  for (int a = 0; a < 4; ++a)
    #pragma unroll
    for (int b = 0; b < 4; ++b) acc[a][b] = f32x4{0.f, 0.f, 0.f, 0.f};

  for (int kb = 0; kb < K; kb += 64) {
    __syncthreads();
    #pragma unroll
    for (int is = 0; is < 4; ++is) {
      const int off = tid * 16 + is * 4096;      // byte offset inside 16KB tile
      const int lrow = off >> 7, lcolB = off & 127;
      g2l16(A  + (size_t)(m0 + lrow) * K + kb + (lcolB >> 1), (char*)Al + off);
      g2l16(Bw + (size_t)(n0 + lrow) * K + kb + (lcolB >> 1), (char*)Bl + off);
    }
    __syncthreads();
    #pragma unroll
    for (int ks = 0; ks < 2; ++ks) {
      bf16x8 af[4], bfr[4];
      #pragma unroll
      for (int mi = 0; mi < 4; ++mi)
        af[mi] = *(const bf16x8*)&Al[((wy * 64 + mi * 16 + frow) << 6) + ks * 32 + fk];
      #pragma unroll
      for (int ni = 0; ni < 4; ++ni)
        bfr[ni] = *(const bf16x8*)&Bl[((wx * 64 + ni * 16 + frow) << 6) + ks * 32 + fk];
      #pragma unroll
      for (int mi = 0; mi < 4; ++mi)
        #pragma unroll
        for (int ni = 0; ni < 4; ++ni)
          acc[mi][ni] = __builtin_amdgcn_mfma_f32_16x16x32_bf16(af[mi], bfr[ni], acc[mi][ni], 0, 0, 0);
    }
  }
  #pragma unroll
  for (int ni = 0; ni < 4; ++ni) {
    const int col = n0 + wx * 64 + ni * 16 + (l & 15);
    float bv = bias1[col];
    if (bias2) bv += bias2[col];
    #pragma unroll
    for (int mi = 0; mi < 4; ++mi) {
      const int row = m0 + wy * 64 + mi * 16 + ((l >> 4) << 2);
      #pragma unroll
      for (int r = 0; r < 4; ++r)
        C[(size_t)(row + r) * N + col] = acc[mi][ni][r] + bv;
    }
  }
}

// ---------------- persistent RNN scan: 1 wave per 16 neurons, MFMA matvec ----
// 64 WGs x 64 threads. WGs 0..31: layer0 slice blk. WGs 32..63: layer1.
// h exchanged as bf16 pairs, value-as-flag (sentinel 0xFFFFFFFF = NaN|NaN).
#define SENT 0xFFFFFFFFu

__device__ __forceinline__ uint32_t aload(const uint32_t* p) {
  return __hip_atomic_load(p, __ATOMIC_RELAXED, __HIP_MEMORY_SCOPE_AGENT);
}
__device__ __forceinline__ void astore(uint32_t* p, uint32_t v) {
  __hip_atomic_store(p, v, __ATOMIC_RELAXED, __HIP_MEMORY_SCOPE_AGENT);
}

// LDS row strides (u16 units) chosen so byte stride/16 mod 8 == 2:
// both the dword scatter-writes and the b128 fragment reads are <=2-way
// bank aliased (free per m136).
template <bool IS_L1>
__device__ __forceinline__ void scan_wave(
    const float* __restrict__ X0,
    const float* __restrict__ W1,   // L0: Whh0 ; L1: Wih1
    const float* __restrict__ W2,   // L1: Whh1
    const float* __restrict__ bi1, const float* __restrict__ bi2,
    uint32_t* __restrict__ H0b, uint32_t* __restrict__ H1b,
    float* __restrict__ hfin, int slice, u16* hs)
{
  constexpr int NB   = IS_L1 ? 32 : 16;     // K blocks of 32
  constexpr int SROW = IS_L1 ? 1040 : 528;  // u16 per batch row (padded)
  const int l  = threadIdx.x;               // 0..63
  const int n  = l & 15;                    // neuron-within-slice / D col
  const int cq = l >> 4;                    // k-quarter 0..3
  const int ng = slice * 16 + n;
  const int fb = n & 3;                     // A-frag batch row (rows 4-15 dup)
  const int pb = cq, pw = n;                // poll: batch pb, words pw+16m

  // B-fragments resident in registers: lane l block j holds
  // W[ng][j*32 + cq*8 + e] as bf16.
  bf16x8 bw[NB];
  #pragma unroll
  for (int j = 0; j < NB; ++j) {
    const float* wrow;
    int koff;
    if constexpr (IS_L1) {
      if (j < 16) { wrow = W1 + (size_t)ng * Hdim; koff = j * 32; }
      else        { wrow = W2 + (size_t)ng * Hdim; koff = (j - 16) * 32; }
    } else        { wrow = W1 + (size_t)ng * Hdim; koff = j * 32; }
    const float4 a = *(const float4*)(wrow + koff + cq * 8);
    const float4 b = *(const float4*)(wrow + koff + cq * 8 + 4);
    bw[j][0] = (__bf16)a.x; bw[j][1] = (__bf16)a.y;
    bw[j][2] = (__bf16)a.z; bw[j][3] = (__bf16)a.w;
    bw[j][4] = (__bf16)b.x; bw[j][5] = (__bf16)b.y;
    bw[j][6] = (__bf16)b.z; bw[j][7] = (__bf16)b.w;
  }
  float bias = 0.f;
  if constexpr (IS_L1) bias = bi1[ng] + bi2[ng];

  uint32_t* const Hout = IS_L1 ? H1b : H0b;

  for (int t = 0; t < Tdim; ++t) {
    float x0v[4];
    if constexpr (!IS_L1) {
      #pragma unroll
      for (int b = 0; b < 4; ++b)
        x0v[b] = X0[((size_t)b * Tdim + t) * Hdim + ng];   // overlaps the poll
    }
    f32x4 ac[4];
    #pragma unroll
    for (int q = 0; q < 4; ++q) ac[q] = f32x4{0.f, 0.f, 0.f, 0.f};

    if constexpr (!IS_L1) {
      if (t > 0) {
        const uint32_t* P = H0b + ((size_t)pb * Tdim + (t - 1)) * 256 + pw;
        uint32_t v[16];
        #pragma unroll
        for (int m = 0; m < 16; ++m) v[m] = aload(P + m * 16);   // all in flight
        #pragma unroll
        for (int m = 0; m < 16; ++m) while (v[m] == SENT) v[m] = aload(P + m * 16);
        __syncthreads();
        #pragma unroll
        for (int m = 0; m < 16; ++m)
          *(uint32_t*)&hs[pb * SROW + 2 * (pw + m * 16)] = v[m];
        __syncthreads();
        #pragma unroll
        for (int j = 0; j < 16; ++j) {
          const bf16x8 af = *(const bf16x8*)&hs[fb * SROW + j * 32 + cq * 8];
          ac[j & 3] = __builtin_amdgcn_mfma_f32_16x16x32_bf16(af, bw[j], ac[j & 3], 0, 0, 0);
        }
      }
    } else {
      const uint32_t* P0 = H0b + ((size_t)pb * Tdim + t) * 256 + pw;
      const uint32_t* P1 = H1b + ((size_t)pb * Tdim + (t - 1)) * 256 + pw;
      uint32_t v[16], u[16];
      #pragma unroll
      for (int m = 0; m < 16; ++m) v[m] = aload(P0 + m * 16);
      if (t > 0) {
        #pragma unroll
        for (int m = 0; m < 16; ++m) u[m] = aload(P1 + m * 16);
      }
      // phase A: h0_t (L0 runs ahead -> usually ready)
      #pragma unroll
      for (int m = 0; m < 16; ++m) while (v[m] == SENT) v[m] = aload(P0 + m * 16);
      __syncthreads();
      #pragma unroll
      for (int m = 0; m < 16; ++m)
        *(uint32_t*)&hs[pb * SROW + 2 * (pw + m * 16)] = v[m];
      __syncthreads();
      #pragma unroll
      for (int j = 0; j < 16; ++j) {
        const bf16x8 af = *(const bf16x8*)&hs[fb * SROW + j * 32 + cq * 8];
        ac[j & 3] = __builtin_amdgcn_mfma_f32_16x16x32_bf16(af, bw[j], ac[j & 3], 0, 0, 0);
      }
      // phase B: h1_{t-1} (the tight self-recurrence chain)
      if (t > 0) {
        #pragma unroll
        for (int m = 0; m < 16; ++m) while (u[m] == SENT) u[m] = aload(P1 + m * 16);
        __syncthreads();
        #pragma unroll
        for (int m = 0; m < 16; ++m)
          *(uint32_t*)&hs[pb * SROW + 512 + 2 * (pw + m * 16)] = u[m];
        __syncthreads();
        #pragma unroll
        for (int j = 16; j < 32; ++j) {
          const bf16x8 af = *(const bf16x8*)&hs[fb * SROW + j * 32 + cq * 8];
          ac[j & 3] = __builtin_amdgcn_mfma_f32_16x16x32_bf16(af, bw[j], ac[j & 3], 0, 0, 0);
        }
      }
    }

    const f32x4 acc = (ac[0] + ac[1]) + (ac[2] + ac[3]);
    // D layout: col = lane&15, row = (lane>>4)*4 + reg -> lanes 0..15 hold
    // batches 0..3 in regs 0..3.
    float hv[4], hp[4];
    #pragma unroll
    for (int r = 0; r < 4; ++r) {
      float ex;
      if constexpr (IS_L1) ex = bias; else ex = x0v[r];
      hv[r] = tanhf(acc[r] + ex);
    }
    #pragma unroll
    for (int r = 0; r < 4; ++r) hp[r] = __shfl_xor(hv[r], 1);
    if (cq == 0) {
      if (!(n & 1)) {
        #pragma unroll
        for (int r = 0; r < 4; ++r) {
          const uint32_t wd = (uint32_t)f2bf(hv[r]) | ((uint32_t)f2bf(hp[r]) << 16);
          astore(&Hout[((size_t)r * Tdim + t) * 256 + (ng >> 1)], wd);
        }
      }
      if (t == Tdim - 1) {
        #pragma unroll
        for (int r = 0; r < 4; ++r)
          hfin[(IS_L1 ? Bdim * Hdim : 0) + r * Hdim + ng] = hv[r];
      }
    }
  }
}

__global__ __launch_bounds__(64, 1) void k_scan(
    const float* __restrict__ X0, const float* __restrict__ W_ih,
    const float* __restrict__ W_hh, const float* __restrict__ b_ih,
    const float* __restrict__ b_hh, uint32_t* __restrict__ H0b,
    uint32_t* __restrict__ H1b, float* __restrict__ hfin)
{
  __shared__ u16 hs[4160];
  const int blk = blockIdx.x;
  if (blk < 32)
    scan_wave<false>(X0, W_hh, nullptr, nullptr, nullptr, H0b, H1b, hfin, blk, hs);
  else
    scan_wave<true>(nullptr, W_ih + Hdim * Hdim, W_hh + Hdim * Hdim,
                    b_ih + Hdim, b_hh + Hdim, H0b, H1b, hfin, blk - 32, hs);
}

// ---------------- launch ----------------
extern "C" void kernel_launch(void* const* d_in, const int* in_sizes, int n_in,
                              void* d_out, int out_size, void* d_ws, size_t ws_size,
                              hipStream_t stream)
{
  const int*   x     = (const int*)d_in[0];
  const float* embed = (const float*)d_in[1];
  const float* W_ih  = (const float*)d_in[2];
  const float* b_ih  = (const float*)d_in[3];
  const float* W_hh  = (const float*)d_in[4];
  const float* b_hh  = (const float*)d_in[5];
  const float* W_out = (const float*)d_in[6];
  const float* b_out = (const float*)d_in[7];
  float* out = (float*)d_out;

  // workspace layout (~75.3 MB)
  char* ws = (char*)d_ws;
  u16* E       = (u16*)ws;                                  // 8192*512 bf16
  u16* Wih0b   = E + (size_t)MROWS * Hdim;                  // 512*512
  u16* Woutb   = Wih0b + Hdim * Hdim;                       // 32000*512
  float* X0    = (float*)(Woutb + (size_t)Vdim * Hdim);     // 8192*512 f32
  uint32_t* H0b = (uint32_t*)(X0 + (size_t)MROWS * Hdim);   // 8192*256 words
  uint32_t* H1b = H0b + (size_t)MROWS * (Hdim / 2);

  k_gather<<<MROWS * (Hdim / 4) / 256, 256, 0, stream>>>(x, embed, E);
  k_f2b<<<(Hdim * Hdim / 4) / 256, 256, 0, stream>>>(W_ih, Wih0b, Hdim * Hdim / 4);
  k_f2b<<<(Vdim * Hdim / 4) / 256, 256, 0, stream>>>(W_out, Woutb, Vdim * Hdim / 4);

  // X0 = E @ Wih0^T + b_ih0 + b_hh0
  k_gemm<<<(MROWS / 128) * (Hdim / 128), 256, 0, stream>>>(
      E, Wih0b, X0, b_ih, b_hh, MROWS, Hdim, Hdim, Hdim / 128);

  hipMemsetAsync(H0b, 0xFF, (size_t)MROWS * (Hdim / 2) * 4, stream);
  hipMemsetAsync(H1b, 0xFF, (size_t)MROWS * (Hdim / 2) * 4, stream);

  float* hfin = out + (size_t)MROWS * Vdim;
  k_scan<<<64, 64, 0, stream>>>(X0, W_ih, W_hh, b_ih, b_hh, H0b, H1b, hfin);

  // out = H1 @ W_out^T + b_out
  k_gemm<<<(MROWS / 128) * (Vdim / 128), 256, 0, stream>>>(
      (const u16*)H1b, Woutb, out, b_out, nullptr, MROWS, Vdim, Hdim, Vdim / 128);
}

// Round 3
// 6846.001 us; speedup vs baseline: 1.4377x; 1.4377x over previous
//
#include <hip/hip_runtime.h>
#include <stdint.h>

#define Bdim 4
#define Tdim 2048
#define Vdim 32000
#define Hdim 512
#define MROWS (Bdim * Tdim)   // 8192

typedef unsigned short u16;
typedef __bf16 bf16x8 __attribute__((ext_vector_type(8)));
typedef float f32x4 __attribute__((ext_vector_type(4)));

__device__ __forceinline__ u16 f2bf(float f) {
  union { float f; uint32_t u; } a; a.f = f;
  uint32_t r = a.u + 0x7FFFu + ((a.u >> 16) & 1u);
  return (u16)(r >> 16);
}

// ---------------- embedding gather -> bf16 ----------------
__global__ void k_gather(const int* __restrict__ x, const float* __restrict__ embed,
                         u16* __restrict__ E) {
  int idx = blockIdx.x * 256 + threadIdx.x;   // one float4 per thread
  int row = idx >> 7;                          // 128 float4 per row
  int c4  = (idx & 127) << 2;
  int tok = x[row];
  const float4 v = *(const float4*)(embed + (size_t)tok * Hdim + c4);
  *(ushort4*)(E + (size_t)row * Hdim + c4) =
      make_ushort4(f2bf(v.x), f2bf(v.y), f2bf(v.z), f2bf(v.w));
}

// ---------------- fp32 -> bf16 convert ----------------
__global__ void k_f2b(const float* __restrict__ in, u16* __restrict__ out, int n4) {
  int idx = blockIdx.x * 256 + threadIdx.x;
  if (idx >= n4) return;
  const float4 v = *(const float4*)(in + (size_t)idx * 4);
  *(ushort4*)(out + (size_t)idx * 4) =
      make_ushort4(f2bf(v.x), f2bf(v.y), f2bf(v.z), f2bf(v.w));
}

// ---------------- bf16 MFMA GEMM: C = A @ Bw^T + bias1 (+bias2) ----------------
__device__ __forceinline__ void g2l16(const void* g, void* l) {
  __builtin_amdgcn_global_load_lds(
      (const __attribute__((address_space(1))) uint32_t*)g,
      (__attribute__((address_space(3))) uint32_t*)l, 16, 0, 0);
}

__global__ __launch_bounds__(256, 2) void k_gemm(
    const u16* __restrict__ A, const u16* __restrict__ Bw, float* __restrict__ C,
    const float* __restrict__ bias1, const float* __restrict__ bias2,
    int M, int N, int K, int ntN)
{
  __shared__ u16 Al[128 * 64];
  __shared__ u16 Bl[128 * 64];
  const int bid = blockIdx.x;
  const int mt = bid / ntN, nt = bid % ntN;
  const int m0 = mt << 7, n0 = nt << 7;
  const int tid = threadIdx.x;
  const int l = tid & 63, w = tid >> 6;
  const int wy = w >> 1, wx = w & 1;
  const int frow = l & 15, fk = (l >> 4) << 3;

  f32x4 acc[4][4];
  #pragma unroll
  for (int a = 0; a < 4; ++a)
    #pragma unroll
    for (int b = 0; b < 4; ++b) acc[a][b] = f32x4{0.f, 0.f, 0.f, 0.f};

  for (int kb = 0; kb < K; kb += 64) {
    __syncthreads();
    #pragma unroll
    for (int is = 0; is < 4; ++is) {
      const int off = tid * 16 + is * 4096;      // byte offset inside 16KB tile
      const int lrow = off >> 7, lcolB = off & 127;
      g2l16(A  + (size_t)(m0 + lrow) * K + kb + (lcolB >> 1), (char*)Al + off);
      g2l16(Bw + (size_t)(n0 + lrow) * K + kb + (lcolB >> 1), (char*)Bl + off);
    }
    __syncthreads();
    #pragma unroll
    for (int ks = 0; ks < 2; ++ks) {
      bf16x8 af[4], bfr[4];
      #pragma unroll
      for (int mi = 0; mi < 4; ++mi)
        af[mi] = *(const bf16x8*)&Al[((wy * 64 + mi * 16 + frow) << 6) + ks * 32 + fk];
      #pragma unroll
      for (int ni = 0; ni < 4; ++ni)
        bfr[ni] = *(const bf16x8*)&Bl[((wx * 64 + ni * 16 + frow) << 6) + ks * 32 + fk];
      #pragma unroll
      for (int mi = 0; mi < 4; ++mi)
        #pragma unroll
        for (int ni = 0; ni < 4; ++ni)
          acc[mi][ni] = __builtin_amdgcn_mfma_f32_16x16x32_bf16(af[mi], bfr[ni], acc[mi][ni], 0, 0, 0);
    }
  }
  #pragma unroll
  for (int ni = 0; ni < 4; ++ni) {
    const int col = n0 + wx * 64 + ni * 16 + (l & 15);
    float bv = bias1[col];
    if (bias2) bv += bias2[col];
    #pragma unroll
    for (int mi = 0; mi < 4; ++mi) {
      const int row = m0 + wy * 64 + mi * 16 + ((l >> 4) << 2);
      #pragma unroll
      for (int r = 0; r < 4; ++r)
        C[(size_t)(row + r) * N + col] = acc[mi][ni][r] + bv;
    }
  }
}

// ---------------- persistent RNN scan ----------------
// 16 WGs x 256 threads (4 waves). WGs 0..7: layer0, 64 neurons each
// (wave w -> 16 neurons). WGs 8..15: layer1. The 256 threads cooperatively
// poll+stage the full h vector (4 dwords/thread, batch-reissued spin); each
// wave then MFMAs its own 16-neuron slice.
// h exchanged as bf16 pairs, value-as-flag (sentinel = NaN|NaN).
#define SENT 0xFFFFFFFFu

__device__ __forceinline__ uint64_t al64(const uint64_t* p) {
  return __hip_atomic_load(p, __ATOMIC_RELAXED, __HIP_MEMORY_SCOPE_AGENT);
}
__device__ __forceinline__ void astore(uint32_t* p, uint32_t v) {
  __hip_atomic_store(p, v, __ATOMIC_RELAXED, __HIP_MEMORY_SCOPE_AGENT);
}
__device__ __forceinline__ bool bad2(uint64_t x) {
  return ((uint32_t)x == SENT) || ((uint32_t)(x >> 32) == SENT);
}
#define SPIN2(va, vb, P)                                          \
  while (bad2(va) || bad2(vb)) {                                  \
    if (bad2(va)) va = al64(P);                                   \
    if (bad2(vb)) vb = al64((P) + 1);                             \
  }

#define ROWDW 264   // dwords per batch row in LDS (8 mod 32 -> 2-way reads)

template <bool IS_L1>
__device__ __forceinline__ void scan_wg(
    const float* __restrict__ X0,
    const float* __restrict__ W1,   // L0: Whh0 ; L1: Wih1
    const float* __restrict__ W2,   // L1: Whh1
    const float* __restrict__ bi1, const float* __restrict__ bi2,
    uint32_t* __restrict__ H0b, uint32_t* __restrict__ H1b,
    float* __restrict__ hfin, int wgs, uint32_t* hsA, uint32_t* hsB)
{
  constexpr int NB = IS_L1 ? 32 : 16;        // K blocks of 32
  const int tid = threadIdx.x;               // 0..255
  const int wv  = tid >> 6;                  // wave 0..3
  const int l   = tid & 63;
  const int n   = l & 15;                    // neuron-within-wave / D col
  const int cq  = l >> 4;                    // k-quarter 0..3
  const int ng  = wgs * 64 + wv * 16 + n;    // global neuron
  const int fb  = n & 3;                     // A-frag batch row (rows 4-15 dup)
  const int pb  = wv;                        // staging: wave == batch
  const int q   = l;                         // 4-dword granule within batch

  // B-fragments resident in registers: lane (n,cq) block j holds
  // W[ng][j*32 + cq*8 + e] as bf16.
  bf16x8 bw[NB];
  #pragma unroll
  for (int j = 0; j < NB; ++j) {
    const float* wrow;
    int koff;
    if constexpr (IS_L1) {
      if (j < 16) { wrow = W1 + (size_t)ng * Hdim; koff = j * 32; }
      else        { wrow = W2 + (size_t)ng * Hdim; koff = (j - 16) * 32; }
    } else        { wrow = W1 + (size_t)ng * Hdim; koff = j * 32; }
    const float4 a = *(const float4*)(wrow + koff + cq * 8);
    const float4 b = *(const float4*)(wrow + koff + cq * 8 + 4);
    bw[j][0] = (__bf16)a.x; bw[j][1] = (__bf16)a.y;
    bw[j][2] = (__bf16)a.z; bw[j][3] = (__bf16)a.w;
    bw[j][4] = (__bf16)b.x; bw[j][5] = (__bf16)b.y;
    bw[j][6] = (__bf16)b.z; bw[j][7] = (__bf16)b.w;
  }
  float bias = 0.f;
  if constexpr (IS_L1) bias = bi1[ng] + bi2[ng];

  const uint64_t *PpA = nullptr, *PpB = nullptr;
  uint64_t vaA = 0, vbA = 0, vaB = 0, vbB = 0;
  if constexpr (IS_L1) {   // initial issue: h0[0]
    PpA = (const uint64_t*)(H0b + ((size_t)pb * Tdim + 0) * 256 + 4 * q);
    vaA = al64(PpA); vbA = al64(PpA + 1);
  }

  #pragma unroll 1
  for (int t = 0; t < Tdim; ++t) {
    uint32_t* sA = hsA + (t & 1) * (4 * ROWDW);
    f32x4 ac[4];
    #pragma unroll
    for (int x = 0; x < 4; ++x) ac[x] = f32x4{0.f, 0.f, 0.f, 0.f};

    if constexpr (!IS_L1) {
      // -------- layer 0 --------
      float x0v[4];
      #pragma unroll
      for (int r = 0; r < 4; ++r)
        x0v[r] = X0[((size_t)r * Tdim + t) * Hdim + ng];   // early, off-path

      if (t > 0) {
        SPIN2(vaA, vbA, PpA);
        uint4 u;
        u.x = (uint32_t)vaA; u.y = (uint32_t)(vaA >> 32);
        u.z = (uint32_t)vbA; u.w = (uint32_t)(vbA >> 32);
        *(uint4*)(sA + pb * ROWDW + 4 * q) = u;
      }
      // prefetch polls for t+1 (reads h0[t]) — in flight across compute
      PpA = (const uint64_t*)(H0b + ((size_t)pb * Tdim + t) * 256 + 4 * q);
      vaA = al64(PpA); vbA = al64(PpA + 1);

      if (t > 0) {
        __syncthreads();
        const u16* sA16 = (const u16*)sA;
        #pragma unroll
        for (int j = 0; j < 16; ++j) {
          const bf16x8 af = *(const bf16x8*)&sA16[fb * (2 * ROWDW) + j * 32 + cq * 8];
          ac[j & 3] = __builtin_amdgcn_mfma_f32_16x16x32_bf16(af, bw[j], ac[j & 3], 0, 0, 0);
        }
      }
      const f32x4 s = (ac[0] + ac[1]) + (ac[2] + ac[3]);
      float hv[4], hp[4];
      #pragma unroll
      for (int r = 0; r < 4; ++r) hv[r] = tanhf(s[r] + x0v[r]);
      #pragma unroll
      for (int r = 0; r < 4; ++r) hp[r] = __shfl_xor(hv[r], 1);
      if (cq == 0) {
        if (!(n & 1)) {
          #pragma unroll
          for (int r = 0; r < 4; ++r) {
            const uint32_t wd = (uint32_t)f2bf(hv[r]) | ((uint32_t)f2bf(hp[r]) << 16);
            astore(&H0b[((size_t)r * Tdim + t) * 256 + (ng >> 1)], wd);
          }
        }
        if (t == Tdim - 1) {
          #pragma unroll
          for (int r = 0; r < 4; ++r) hfin[r * Hdim + ng] = hv[r];
        }
      }
    } else {
      // -------- layer 1: self-recurrence (B) first, late-arriving h0 (A) last
      uint32_t* sB = hsB + (t & 1) * (4 * ROWDW);
      if (t > 0) {
        SPIN2(vaB, vbB, PpB);
        uint4 u;
        u.x = (uint32_t)vaB; u.y = (uint32_t)(vaB >> 32);
        u.z = (uint32_t)vbB; u.w = (uint32_t)(vbB >> 32);
        *(uint4*)(sB + pb * ROWDW + 4 * q) = u;
        __syncthreads();
        const u16* sB16 = (const u16*)sB;
        #pragma unroll
        for (int j = 16; j < 32; ++j) {
          const bf16x8 af = *(const bf16x8*)&sB16[fb * (2 * ROWDW) + (j - 16) * 32 + cq * 8];
          ac[j & 3] = __builtin_amdgcn_mfma_f32_16x16x32_bf16(af, bw[j], ac[j & 3], 0, 0, 0);
        }
      }
      // phase A: h0[t]
      SPIN2(vaA, vbA, PpA);
      {
        uint4 u;
        u.x = (uint32_t)vaA; u.y = (uint32_t)(vaA >> 32);
        u.z = (uint32_t)vbA; u.w = (uint32_t)(vbA >> 32);
        *(uint4*)(sA + pb * ROWDW + 4 * q) = u;
      }
      {  // prefetch A for t+1
        const int tn = (t + 1 < Tdim) ? t + 1 : t;
        PpA = (const uint64_t*)(H0b + ((size_t)pb * Tdim + tn) * 256 + 4 * q);
        vaA = al64(PpA); vbA = al64(PpA + 1);
      }
      __syncthreads();
      const u16* sA16 = (const u16*)sA;
      #pragma unroll
      for (int j = 0; j < 16; ++j) {
        const bf16x8 af = *(const bf16x8*)&sA16[fb * (2 * ROWDW) + j * 32 + cq * 8];
        ac[j & 3] = __builtin_amdgcn_mfma_f32_16x16x32_bf16(af, bw[j], ac[j & 3], 0, 0, 0);
      }
      const f32x4 s = (ac[0] + ac[1]) + (ac[2] + ac[3]);
      float hv[4], hp[4];
      #pragma unroll
      for (int r = 0; r < 4; ++r) hv[r] = tanhf(s[r] + bias);
      #pragma unroll
      for (int r = 0; r < 4; ++r) hp[r] = __shfl_xor(hv[r], 1);
      if (cq == 0) {
        if (!(n & 1)) {
          #pragma unroll
          for (int r = 0; r < 4; ++r) {
            const uint32_t wd = (uint32_t)f2bf(hv[r]) | ((uint32_t)f2bf(hp[r]) << 16);
            astore(&H1b[((size_t)r * Tdim + t) * 256 + (ng >> 1)], wd);
          }
        }
        if (t == Tdim - 1) {
          #pragma unroll
          for (int r = 0; r < 4; ++r) hfin[Bdim * Hdim + r * Hdim + ng] = hv[r];
        }
      }
      // prefetch B for t+1 (reads h1[t], just stored)
      PpB = (const uint64_t*)(H1b + ((size_t)pb * Tdim + t) * 256 + 4 * q);
      vaB = al64(PpB); vbB = al64(PpB + 1);
    }
  }
}

__global__ __launch_bounds__(256, 1) void k_scan(
    const float* __restrict__ X0, const float* __restrict__ W_ih,
    const float* __restrict__ W_hh, const float* __restrict__ b_ih,
    const float* __restrict__ b_hh, uint32_t* __restrict__ H0b,
    uint32_t* __restrict__ H1b, float* __restrict__ hfin)
{
  __shared__ __align__(16) uint32_t hsA[2 * 4 * ROWDW];
  __shared__ __align__(16) uint32_t hsB[2 * 4 * ROWDW];
  const int blk = blockIdx.x;
  if (blk < 8)
    scan_wg<false>(X0, W_hh, nullptr, nullptr, nullptr, H0b, H1b, hfin, blk, hsA, hsB);
  else
    scan_wg<true>(nullptr, W_ih + Hdim * Hdim, W_hh + Hdim * Hdim,
                  b_ih + Hdim, b_hh + Hdim, H0b, H1b, hfin, blk - 8, hsA, hsB);
}

// ---------------- launch ----------------
extern "C" void kernel_launch(void* const* d_in, const int* in_sizes, int n_in,
                              void* d_out, int out_size, void* d_ws, size_t ws_size,
                              hipStream_t stream)
{
  const int*   x     = (const int*)d_in[0];
  const float* embed = (const float*)d_in[1];
  const float* W_ih  = (const float*)d_in[2];
  const float* b_ih  = (const float*)d_in[3];
  const float* W_hh  = (const float*)d_in[4];
  const float* b_hh  = (const float*)d_in[5];
  const float* W_out = (const float*)d_in[6];
  const float* b_out = (const float*)d_in[7];
  float* out = (float*)d_out;

  // workspace layout (~75.3 MB)
  char* ws = (char*)d_ws;
  u16* E       = (u16*)ws;                                  // 8192*512 bf16
  u16* Wih0b   = E + (size_t)MROWS * Hdim;                  // 512*512
  u16* Woutb   = Wih0b + Hdim * Hdim;                       // 32000*512
  float* X0    = (float*)(Woutb + (size_t)Vdim * Hdim);     // 8192*512 f32
  uint32_t* H0b = (uint32_t*)(X0 + (size_t)MROWS * Hdim);   // 8192*256 words
  uint32_t* H1b = H0b + (size_t)MROWS * (Hdim / 2);

  k_gather<<<MROWS * (Hdim / 4) / 256, 256, 0, stream>>>(x, embed, E);
  k_f2b<<<(Hdim * Hdim / 4) / 256, 256, 0, stream>>>(W_ih, Wih0b, Hdim * Hdim / 4);
  k_f2b<<<(Vdim * Hdim / 4) / 256, 256, 0, stream>>>(W_out, Woutb, Vdim * Hdim / 4);

  // X0 = E @ Wih0^T + b_ih0 + b_hh0
  k_gemm<<<(MROWS / 128) * (Hdim / 128), 256, 0, stream>>>(
      E, Wih0b, X0, b_ih, b_hh, MROWS, Hdim, Hdim, Hdim / 128);

  hipMemsetAsync(H0b, 0xFF, (size_t)MROWS * (Hdim / 2) * 4, stream);
  hipMemsetAsync(H1b, 0xFF, (size_t)MROWS * (Hdim / 2) * 4, stream);

  float* hfin = out + (size_t)MROWS * Vdim;
  k_scan<<<16, 256, 0, stream>>>(X0, W_ih, W_hh, b_ih, b_hh, H0b, H1b, hfin);

  // out = H1 @ W_out^T + b_out
  k_gemm<<<(MROWS / 128) * (Vdim / 128), 256, 0, stream>>>(
      (const u16*)H1b, Woutb, out, b_out, nullptr, MROWS, Vdim, Hdim, Vdim / 128);
}